// Round 8
// baseline (1880.285 us; speedup 1.0000x reference)
//
#include <hip/hip_runtime.h>
#include <math.h>

typedef unsigned int u32;

// ---------- bf16 helpers ----------
__device__ __forceinline__ u32 pk2(float a, float b){
    u32 ua=__float_as_uint(a), ub=__float_as_uint(b);
    u32 ra=(ua + 0x7fffu + ((ua>>16)&1u))>>16;
    u32 rb=(ub + 0x7fffu + ((ub>>16)&1u))>>16;
    return ra | (rb<<16);
}
__device__ __forceinline__ float lo16(u32 p){ return __uint_as_float(p<<16); }
__device__ __forceinline__ float hi16(u32 p){ return __uint_as_float(p & 0xffff0000u); }

// packed bf16x2 dot-accumulate: c += a.x*b.x + a.y*b.y
#if __has_builtin(__builtin_amdgcn_fdot2_f32_bf16)
__device__ __forceinline__ float dot2bf(u32 a, u32 b, float c){
    float d;
    asm("v_dot2_f32_bf16 %0, %1, %2, %3" : "=v"(d) : "v"(a), "v"(b), "v"(c));
    return d;
}
#else
__device__ __forceinline__ float dot2bf(u32 a, u32 b, float c){
    return fmaf(hi16(a), hi16(b), fmaf(lo16(a), lo16(b), c));
}
#endif

// ---------- W convert: fp32 [o][i][jg][c] -> bf16 pairs, layout [i][jj][cb][q][o] ----------
template<int I,int Di,int O,int Do>
__global__ void k_conv(const float* __restrict__ W, u32* __restrict__ Wb){
    constexpr int CB = Di/8, LPO = Do/16;
    const int n = O*I*Do*Di/2;
    for (int t = blockIdx.x*blockDim.x+threadIdx.x; t < n; t += gridDim.x*blockDim.x){
        int cw = t & 3;
        int u4 = t >> 2;
        int o  = u4 % O;
        int r1 = u4 / O;
        int q  = r1 % LPO;
        int r2 = r1 / LPO;
        int cb = r2 % CB;
        int r3 = r2 / CB;
        int jj = r3 & 15;
        int i  = r3 >> 4;
        int jg = q*16 + jj;
        int c  = cb*8 + cw*2;
        const float* s = W + ((size_t)(o*I + i)*Do + jg)*Di + c;
        Wb[t] = pk2(s[0], s[1]);
    }
}

// ---------- fused layer, direct-from-L2 W reads, 16 waves ----------
// 16 waves: WI waves split the i-axis (multiplicity-1 W reads); e-group w/WI owns
// Ew=4/(16/WI) elements. Lane l: o=l/LPO, d-block q=l%LPO (16 d's).
// W read straight from global (L2-resident) with a 2-group register pipeline.
// Per-pass cross-wave s-reduction: atomicAdd into lane-major SS[e][j*64+l].
// vs carry (affine-logit identity) in lane-major X[e][j*64+l].
template<int I,int Di,int O,int Do,int WI,int FIN>
__device__ __forceinline__ void run_layer(const u32* __restrict__ Wb,
    float (*X)[1024], float (*SS)[1024], u32 (*hp)[512], float* __restrict__ out,
    int bid, int w, int l, int tid)
{
    constexpr int CB  = Di/8;
    constexpr int LPO = Do/16;
    constexpr int ACT = O*LPO;
    constexpr int GR  = LPO*O;        // uint4 granule per (j,cb)
    constexpr int ES  = 16/WI;
    constexpr int Ew  = 4/ES;
    constexpr int NSL = 16*CB;        // uint4 slots per i per lane
    constexpr int NG  = NSL/4;        // groups of 4 slots
    static_assert(Ew >= 1, "");

    const int i_loc = w % WI;
    const int e0    = (w/WI)*Ew;
    const bool act  = l < ACT;
    const int qL    = act ? (l % LPO) : 0;
    const int oL    = act ? (l / LPO) : 0;
    const int lnoff = qL*O + oL;      // per-lane uint4 offset within granule
    const uint4* W4 = (const uint4*)Wb;

    for (int r = 0; r < 3; ++r){
        u32 vp[Ew][8];
        if (r > 0){
            #pragma unroll
            for (int eu=0; eu<Ew; ++eu)
                #pragma unroll
                for (int jj=0; jj<8; ++jj)
                    vp[eu][jj] = pk2(X[e0+eu][(2*jj)*64 + l], X[e0+eu][(2*jj+1)*64 + l]);
        }

        float sacc[Ew][16];
        #pragma unroll
        for (int eu=0; eu<Ew; ++eu)
            #pragma unroll
            for (int j=0; j<16; ++j) sacc[eu][j] = 0.f;

        for (int k = 0; k < I/WI; ++k){
            const int i = i_loc + WI*k;
            const size_t bi = (size_t)i*NSL*GR + lnoff;

            // h fragment, packed bf16 pairs (dot2 operand)
            u32 hk[Ew][Di/2];
            #pragma unroll
            for (int eu=0; eu<Ew; ++eu)
                #pragma unroll
                for (int t4=0; t4<Di/8; ++t4){
                    uint4 hv = *(const uint4*)&hp[e0+eu][i*(Di/2) + 4*t4];
                    hk[eu][4*t4+0]=hv.x; hk[eu][4*t4+1]=hv.y;
                    hk[eu][4*t4+2]=hv.z; hk[eu][4*t4+3]=hv.w;
                }

            float xh[Ew][16];
            #pragma unroll
            for (int eu=0; eu<Ew; ++eu)
                #pragma unroll
                for (int j=0; j<16; ++j) xh[eu][j] = 0.f;

            uint4 bufA[4], bufB[4];
            auto ldg = [&](int g, uint4 (&buf)[4]){
                #pragma unroll
                for (int s=0; s<4; ++s)
                    buf[s] = W4[bi + (size_t)(4*g+s)*GR];
            };
            auto cmp = [&](int g, uint4 (&buf)[4]){
                #pragma unroll
                for (int s=0; s<4; ++s){
                    const int slot = 4*g+s, j = slot/CB, cb = slot%CB;
                    #pragma unroll
                    for (int eu=0; eu<Ew; ++eu){
                        float t = xh[eu][j];
                        t = dot2bf(buf[s].x, hk[eu][cb*4+0], t);
                        t = dot2bf(buf[s].y, hk[eu][cb*4+1], t);
                        t = dot2bf(buf[s].z, hk[eu][cb*4+2], t);
                        t = dot2bf(buf[s].w, hk[eu][cb*4+3], t);
                        xh[eu][j] = t;
                    }
                }
            };

            ldg(0, bufA);
            #pragma unroll
            for (int g=0; g<NG; ++g){
                if (g & 1){ if (g+1<NG) ldg(g+1, bufA); cmp(g, bufB); }
                else      { if (g+1<NG) ldg(g+1, bufB); cmp(g, bufA); }
            }

            float cc[Ew];
            if (r == 0){
                #pragma unroll
                for (int eu=0; eu<Ew; ++eu) cc[eu] = 1.f;   // 1/O folded at squash
            } else {
                #pragma unroll
                for (int eu=0; eu<Ew; ++eu){
                    float lp = 0.f;
                    #pragma unroll
                    for (int jj=0; jj<8; ++jj)
                        lp += lo16(vp[eu][jj])*xh[eu][2*jj] + hi16(vp[eu][jj])*xh[eu][2*jj+1];
                    if constexpr (LPO>=2) lp += __shfl_xor(lp,1,64);
                    if constexpr (LPO>=4) lp += __shfl_xor(lp,2,64);
                    float ev = act ? __expf(lp) : 0.f;
                    float tot = ev;                          // each o counted LPO times
                    tot+=__shfl_xor(tot,1,64);  tot+=__shfl_xor(tot,2,64);
                    tot+=__shfl_xor(tot,4,64);  tot+=__shfl_xor(tot,8,64);
                    tot+=__shfl_xor(tot,16,64); tot+=__shfl_xor(tot,32,64);
                    cc[eu] = ev*(float)LPO/tot;
                }
            }
            #pragma unroll
            for (int eu=0; eu<Ew; ++eu)
                #pragma unroll
                for (int j=0; j<16; ++j) sacc[eu][j] += cc[eu]*xh[eu][j];
        }

        // cross-wave reduction (lane-major: 2 lanes/bank, conflict-free)
        if (act){
            #pragma unroll
            for (int eu=0; eu<Ew; ++eu)
                #pragma unroll
                for (int j=0; j<16; ++j)
                    atomicAdd(&SS[e0+eu][j*64 + l], sacc[eu][j]);
        }
        __syncthreads();

        // squash: wave e handles element e
        if (w < 4){
            const int e = w;
            float s[16];
            #pragma unroll
            for (int j=0; j<16; ++j){
                float t = SS[e][j*64 + l];
                if (r == 0) t *= (1.0f/(float)O);
                s[j] = t;
            }
            float n2 = 0.f;
            #pragma unroll
            for (int j=0; j<16; ++j) n2 += s[j]*s[j];
            if constexpr (LPO>=2) n2 += __shfl_xor(n2,1,64);
            if constexpr (LPO>=4) n2 += __shfl_xor(n2,2,64);
            float nrm   = sqrtf(n2);
            float scale = n2/((1.f+n2)*(nrm+1e-8f));

            if (r < 2){
                if (act){
                    #pragma unroll
                    for (int j=0; j<16; ++j){
                        float old = (r==0) ? 0.f : X[e][j*64 + l];
                        X[e][j*64 + l] = old + scale*s[j];   // vs += v
                    }
                }
            } else if constexpr (FIN == 0){
                if (act){
                    #pragma unroll
                    for (int kk=0; kk<8; ++kk)
                        hp[e][oL*(Do/2) + qL*8 + kk] = pk2(scale*s[2*kk], scale*s[2*kk+1]);
                }
            } else {
                float q = 0.f;
                #pragma unroll
                for (int j=0; j<16; ++j){ float vj = scale*s[j]; q += vj*vj; }
                if constexpr (LPO>=2) q += __shfl_xor(q,1,64);
                if constexpr (LPO>=4) q += __shfl_xor(q,2,64);
                if (act && (l % LPO) == 0)
                    out[(size_t)(bid*4 + e)*O + oL] = sqrtf(q);
            }
        }
        __syncthreads();
        // zero SS for next pass
        for (int t = tid; t < 4096; t += 1024) ((float*)SS)[t] = 0.f;
        __syncthreads();
    }
}

__global__ __launch_bounds__(1024,1) void caps_main(
    const float* __restrict__ x, const u32* __restrict__ Wb0,
    const u32* __restrict__ Wb1, const u32* __restrict__ Wb2,
    float* __restrict__ out)
{
    __shared__ __align__(16) float X[4][1024];   // vs state (lane-major)
    __shared__ __align__(16) float SS[4][1024];  // s accumulation (lane-major)
    __shared__ __align__(16) u32 hp[4][512];     // h (bf16 pairs)

    const int tid = threadIdx.x;
    const int w = tid>>6, l = tid&63;
    const int bid = blockIdx.x;

    {   // pack x -> hp (bf16), zero SS
        const float2* xs = (const float2*)(x + (size_t)bid*4*1024);
        for (int k = tid; k < 2048; k += 1024){
            float2 f = xs[k];
            ((u32*)hp)[k] = pk2(f.x, f.y);
        }
        for (int k = tid; k < 4096; k += 1024) ((float*)SS)[k] = 0.f;
    }
    __syncthreads();

    run_layer<128, 8,64,16,16,0>(Wb0, X, SS, hp, out, bid, w, l, tid);
    run_layer< 64,16,32,32,16,0>(Wb1, X, SS, hp, out, bid, w, l, tid);
    run_layer< 32,32,10,64,16,1>(Wb2, X, SS, hp, out, bid, w, l, tid);
}

// ---------------- fallback (round-2 kernel, known-pass) ----------------
template<int I, int Di, int O, int Do, bool FINAL>
__device__ __forceinline__ void fb_layer(const float* __restrict__ W, float* __restrict__ hl,
                                         float* __restrict__ out, int e, int l) {
    constexpr int LPO = Do / 16;
    constexpr int ACT = O * LPO;
    const int o  = l / LPO;
    const int d0 = (l % LPO) * 16;
    const bool act = (l < ACT);
    float vs[16];
    #pragma unroll
    for (int j = 0; j < 16; ++j) vs[j] = 0.f;
    for (int r = 0; r < 3; ++r) {
        float sacc[16];
        #pragma unroll
        for (int j = 0; j < 16; ++j) sacc[j] = 0.f;
        for (int i = 0; i < I; ++i) {
            if ((i & 15) == 0) __syncthreads();
            float xh[16];
            #pragma unroll
            for (int j = 0; j < 16; ++j) xh[j] = 0.f;
            if (act) {
                const float* wb = W + ((size_t)(o * I + i) * Do + d0) * Di;
                #pragma unroll
                for (int j = 0; j < 16; ++j) {
                    const float4* wr = (const float4*)(wb + j * Di);
                    float acc = 0.f;
                    #pragma unroll
                    for (int c4 = 0; c4 < Di / 4; ++c4) {
                        float4 wv = wr[c4];
                        float4 hv = *(const float4*)(hl + i * Di + c4 * 4);
                        acc += wv.x*hv.x + wv.y*hv.y + wv.z*hv.z + wv.w*hv.w;
                    }
                    xh[j] = acc;
                }
            }
            float cc;
            if (r == 0) cc = 1.0f;
            else {
                float lp = 0.f;
                #pragma unroll
                for (int j = 0; j < 16; ++j) lp += vs[j] * xh[j];
                if constexpr (LPO >= 2) lp += __shfl_xor(lp, 1, 64);
                if constexpr (LPO >= 4) lp += __shfl_xor(lp, 2, 64);
                float ev = act ? __expf(lp) : 0.f;
                float tot = ev;
                tot += __shfl_xor(tot,1,64); tot += __shfl_xor(tot,2,64);
                tot += __shfl_xor(tot,4,64); tot += __shfl_xor(tot,8,64);
                tot += __shfl_xor(tot,16,64); tot += __shfl_xor(tot,32,64);
                cc = ev * (float)LPO / tot;
            }
            #pragma unroll
            for (int j = 0; j < 16; ++j) sacc[j] += cc * xh[j];
        }
        if (r == 0) {
            #pragma unroll
            for (int j = 0; j < 16; ++j) sacc[j] *= (1.0f / O);
        }
        float n2 = 0.f;
        #pragma unroll
        for (int j = 0; j < 16; ++j) n2 += sacc[j] * sacc[j];
        if constexpr (LPO >= 2) n2 += __shfl_xor(n2, 1, 64);
        if constexpr (LPO >= 4) n2 += __shfl_xor(n2, 2, 64);
        float nrm = sqrtf(n2);
        float scale = n2 / ((1.f + n2) * (nrm + 1e-8f));
        if (r < 2) {
            #pragma unroll
            for (int j = 0; j < 16; ++j) vs[j] += scale * sacc[j];
        } else {
            if constexpr (FINAL) {
                float q = 0.f;
                #pragma unroll
                for (int j = 0; j < 16; ++j) { float vj = scale*sacc[j]; q += vj*vj; }
                if constexpr (LPO >= 2) q += __shfl_xor(q, 1, 64);
                if constexpr (LPO >= 4) q += __shfl_xor(q, 2, 64);
                if (act && (l % LPO) == 0) out[(size_t)e * O + o] = sqrtf(q);
            } else {
                __syncthreads();
                if (act) {
                    #pragma unroll
                    for (int j = 0; j < 16; ++j) hl[o * Do + d0 + j] = scale * sacc[j];
                }
                __syncthreads();
            }
        }
    }
}

__global__ __launch_bounds__(256) void fb_caps(const float* __restrict__ x,
                                               const float* __restrict__ W0,
                                               const float* __restrict__ W1,
                                               const float* __restrict__ W2,
                                               float* __restrict__ out) {
    __shared__ float hsh[4][1024];
    const int w = threadIdx.x >> 6;
    const int l = threadIdx.x & 63;
    const int e = blockIdx.x * 4 + w;
    float* hl = hsh[w];
    const float4* xr = (const float4*)(x + (size_t)e * 1024);
    float4* h4 = (float4*)hl;
    #pragma unroll
    for (int k = 0; k < 4; ++k) h4[l + 64 * k] = xr[l + 64 * k];
    __syncthreads();
    fb_layer<128, 8, 64, 16, false>(W0, hl, out, e, l);
    fb_layer<64, 16, 32, 32, false>(W1, hl, out, e, l);
    fb_layer<32, 32, 10, 64, true >(W2, hl, out, e, l);
}

extern "C" void kernel_launch(void* const* d_in, const int* in_sizes, int n_in,
                              void* d_out, int out_size, void* d_ws, size_t ws_size,
                              hipStream_t stream) {
    const float* x  = (const float*)d_in[0];   // [1024,1024]
    const float* W0 = (const float*)d_in[1];   // [64,128,16,8]
    const float* W1 = (const float*)d_in[2];   // [32,64,32,16]
    const float* W2 = (const float*)d_in[3];   // [10,32,64,32]
    float* out = (float*)d_out;                // [1024,10]

    const size_t DW0 = (size_t)64*128*16*8/2;   // u32 counts
    const size_t DW1 = (size_t)32*64*32*16/2;
    const size_t DW2 = (size_t)10*32*64*32/2;
    const size_t need = (DW0+DW1+DW2)*4;        // ~5.5 MB

    if (ws_size < need) {                       // safety net: proven slow path
        fb_caps<<<256, 256, 0, stream>>>(x, W0, W1, W2, out);
        return;
    }

    u32* Wb0 = (u32*)d_ws;
    u32* Wb1 = Wb0 + DW0;
    u32* Wb2 = Wb1 + DW1;

    k_conv<128, 8,64,16><<<512,256,0,stream>>>(W0, Wb0);
    k_conv< 64,16,32,32><<<512,256,0,stream>>>(W1, Wb1);
    k_conv< 32,32,10,64><<<512,256,0,stream>>>(W2, Wb2);

    caps_main<<<256, 1024, 0, stream>>>(x, Wb0, Wb1, Wb2, out);
}

// Round 9
// 747.227 us; speedup vs baseline: 2.5164x; 2.5164x over previous
//
#include <hip/hip_runtime.h>
#include <math.h>

typedef unsigned int u32;

// ---------- bf16 helpers ----------
__device__ __forceinline__ u32 pk2(float a, float b){
    u32 ua=__float_as_uint(a), ub=__float_as_uint(b);
    u32 ra=(ua + 0x7fffu + ((ua>>16)&1u))>>16;
    u32 rb=(ub + 0x7fffu + ((ub>>16)&1u))>>16;
    return ra | (rb<<16);
}
__device__ __forceinline__ float lo16(u32 p){ return __uint_as_float(p<<16); }
__device__ __forceinline__ float hi16(u32 p){ return __uint_as_float(p & 0xffff0000u); }

// packed bf16x2 dot-accumulate: c += a.x*b.x + a.y*b.y
#if __has_builtin(__builtin_amdgcn_fdot2_f32_bf16)
__device__ __forceinline__ float dot2bf(u32 a, u32 b, float c){
    float d;
    asm("v_dot2_f32_bf16 %0, %1, %2, %3" : "=v"(d) : "v"(a), "v"(b), "v"(c));
    return d;
}
#else
__device__ __forceinline__ float dot2bf(u32 a, u32 b, float c){
    return fmaf(hi16(a), hi16(b), fmaf(lo16(a), lo16(b), c));
}
#endif

// ---------- W convert: fp32 [o][i][jg][c] -> bf16 pairs, layout [i][jj][cb][q][o] ----------
template<int I,int Di,int O,int Do>
__global__ void k_conv(const float* __restrict__ W, u32* __restrict__ Wb){
    constexpr int CB = Di/8, LPO = Do/16;
    const int n = O*I*Do*Di/2;
    for (int t = blockIdx.x*blockDim.x+threadIdx.x; t < n; t += gridDim.x*blockDim.x){
        int cw = t & 3;
        int u4 = t >> 2;
        int o  = u4 % O;
        int r1 = u4 / O;
        int q  = r1 % LPO;
        int r2 = r1 / LPO;
        int cb = r2 % CB;
        int r3 = r2 / CB;
        int jj = r3 & 15;
        int i  = r3 >> 4;
        int jg = q*16 + jj;
        int c  = cb*8 + cw*2;
        const float* s = W + ((size_t)(o*I + i)*Do + jg)*Di + c;
        Wb[t] = pk2(s[0], s[1]);
    }
}

// ---------- fused layer: 8 waves, 2 elements/block, i-split 8 ways ----------
// Wave w owns i = w, w+8, ... for BOTH elements (each W load feeds 2x16 dot2).
// Lane l: o=l/LPO, d-block q=l%LPO. W read direct from global (L2-resident)
// with a 2-group register pipeline. Cross-wave s-reduce: atomicAdd into
// lane-major SS[e][j*64+l] (2 lanes/bank = free). vs carry in X[e][j*64+l].
template<int I,int Di,int O,int Do,int FIN>
__device__ __forceinline__ void run_layer(const u32* __restrict__ Wb,
    float (*X)[1024], float (*SS)[1024], u32 (*hp)[512], float* __restrict__ out,
    int bid, int w, int l, int tid)
{
    constexpr int CB  = Di/8;
    constexpr int LPO = Do/16;
    constexpr int ACT = O*LPO;
    constexpr int GR  = LPO*O;        // uint4 granule per (j,cb)
    constexpr int NSL = 16*CB;        // uint4 slots per i per lane
    constexpr int NG  = NSL/4;        // groups of 4 slots
    constexpr int Ew  = 2;

    const bool act  = l < ACT;
    const int qL    = act ? (l % LPO) : 0;
    const int oL    = act ? (l / LPO) : 0;
    const int lnoff = qL*O + oL;      // per-lane uint4 offset within granule
    const uint4* W4 = (const uint4*)Wb;

    for (int r = 0; r < 3; ++r){
        u32 vp[Ew][8];
        if (r > 0){
            #pragma unroll
            for (int eu=0; eu<Ew; ++eu)
                #pragma unroll
                for (int jj=0; jj<8; ++jj)
                    vp[eu][jj] = pk2(X[eu][(2*jj)*64 + l], X[eu][(2*jj+1)*64 + l]);
        }

        float sacc[Ew][16];
        #pragma unroll
        for (int eu=0; eu<Ew; ++eu)
            #pragma unroll
            for (int j=0; j<16; ++j) sacc[eu][j] = 0.f;

        for (int k = 0; k < I/8; ++k){
            const int i = w + 8*k;
            const size_t bi = (size_t)i*NSL*GR + lnoff;

            // h fragment, packed bf16 pairs (dot2 operand)
            u32 hk[Ew][Di/2];
            #pragma unroll
            for (int eu=0; eu<Ew; ++eu)
                #pragma unroll
                for (int t4=0; t4<Di/8; ++t4){
                    uint4 hv = *(const uint4*)&hp[eu][i*(Di/2) + 4*t4];
                    hk[eu][4*t4+0]=hv.x; hk[eu][4*t4+1]=hv.y;
                    hk[eu][4*t4+2]=hv.z; hk[eu][4*t4+3]=hv.w;
                }

            float xh[Ew][16];
            #pragma unroll
            for (int eu=0; eu<Ew; ++eu)
                #pragma unroll
                for (int j=0; j<16; ++j) xh[eu][j] = 0.f;

            uint4 bufA[4], bufB[4];
            auto ldg = [&](int g, uint4 (&buf)[4]){
                #pragma unroll
                for (int s=0; s<4; ++s)
                    buf[s] = W4[bi + (size_t)(4*g+s)*GR];
            };
            auto cmp = [&](int g, uint4 (&buf)[4]){
                #pragma unroll
                for (int s=0; s<4; ++s){
                    const int slot = 4*g+s, j = slot/CB, cb = slot%CB;
                    #pragma unroll
                    for (int eu=0; eu<Ew; ++eu){
                        float t = xh[eu][j];
                        t = dot2bf(buf[s].x, hk[eu][cb*4+0], t);
                        t = dot2bf(buf[s].y, hk[eu][cb*4+1], t);
                        t = dot2bf(buf[s].z, hk[eu][cb*4+2], t);
                        t = dot2bf(buf[s].w, hk[eu][cb*4+3], t);
                        xh[eu][j] = t;
                    }
                }
            };

            ldg(0, bufA);
            #pragma unroll
            for (int g=0; g<NG; ++g){
                if (g & 1){ if (g+1<NG) ldg(g+1, bufA); cmp(g, bufB); }
                else      { if (g+1<NG) ldg(g+1, bufB); cmp(g, bufA); }
            }

            float cc[Ew];
            if (r == 0){
                #pragma unroll
                for (int eu=0; eu<Ew; ++eu) cc[eu] = 1.f;   // 1/O folded at squash
            } else {
                #pragma unroll
                for (int eu=0; eu<Ew; ++eu){
                    float lp = 0.f;
                    #pragma unroll
                    for (int jj=0; jj<8; ++jj)
                        lp += lo16(vp[eu][jj])*xh[eu][2*jj] + hi16(vp[eu][jj])*xh[eu][2*jj+1];
                    if constexpr (LPO>=2) lp += __shfl_xor(lp,1,64);
                    if constexpr (LPO>=4) lp += __shfl_xor(lp,2,64);
                    float ev = act ? __expf(lp) : 0.f;
                    float tot = ev;                          // each o counted LPO times
                    tot+=__shfl_xor(tot,1,64);  tot+=__shfl_xor(tot,2,64);
                    tot+=__shfl_xor(tot,4,64);  tot+=__shfl_xor(tot,8,64);
                    tot+=__shfl_xor(tot,16,64); tot+=__shfl_xor(tot,32,64);
                    cc[eu] = ev*(float)LPO/tot;
                }
            }
            #pragma unroll
            for (int eu=0; eu<Ew; ++eu)
                #pragma unroll
                for (int j=0; j<16; ++j) sacc[eu][j] += cc[eu]*xh[eu][j];
        }

        // cross-wave reduction (lane-major: 2 lanes/bank, conflict-free)
        if (act){
            #pragma unroll
            for (int eu=0; eu<Ew; ++eu)
                #pragma unroll
                for (int j=0; j<16; ++j)
                    atomicAdd(&SS[eu][j*64 + l], sacc[eu][j]);
        }
        __syncthreads();

        // squash: wave e handles element e (e = 0,1)
        if (w < Ew){
            const int e = w;
            float s[16];
            #pragma unroll
            for (int j=0; j<16; ++j){
                float t = SS[e][j*64 + l];
                if (r == 0) t *= (1.0f/(float)O);
                s[j] = t;
            }
            float n2 = 0.f;
            #pragma unroll
            for (int j=0; j<16; ++j) n2 += s[j]*s[j];
            if constexpr (LPO>=2) n2 += __shfl_xor(n2,1,64);
            if constexpr (LPO>=4) n2 += __shfl_xor(n2,2,64);
            float nrm   = sqrtf(n2);
            float scale = n2/((1.f+n2)*(nrm+1e-8f));

            if (r < 2){
                if (act){
                    #pragma unroll
                    for (int j=0; j<16; ++j){
                        float old = (r==0) ? 0.f : X[e][j*64 + l];
                        X[e][j*64 + l] = old + scale*s[j];   // vs += v
                    }
                }
            } else if constexpr (FIN == 0){
                if (act){
                    #pragma unroll
                    for (int kk=0; kk<8; ++kk)
                        hp[e][oL*(Do/2) + qL*8 + kk] = pk2(scale*s[2*kk], scale*s[2*kk+1]);
                }
            } else {
                float q = 0.f;
                #pragma unroll
                for (int j=0; j<16; ++j){ float vj = scale*s[j]; q += vj*vj; }
                if constexpr (LPO>=2) q += __shfl_xor(q,1,64);
                if constexpr (LPO>=4) q += __shfl_xor(q,2,64);
                if (act && (l % LPO) == 0)
                    out[(size_t)(bid*2 + e)*O + oL] = sqrtf(q);
            }
        }
        __syncthreads();
        // zero SS for next pass
        for (int t = tid; t < 2048; t += 512) ((float*)SS)[t] = 0.f;
        __syncthreads();
    }
}

__global__ __launch_bounds__(512,2) void caps_main(
    const float* __restrict__ x, const u32* __restrict__ Wb0,
    const u32* __restrict__ Wb1, const u32* __restrict__ Wb2,
    float* __restrict__ out)
{
    __shared__ __align__(16) float X[2][1024];   // vs state (lane-major)
    __shared__ __align__(16) float SS[2][1024];  // s accumulation (lane-major)
    __shared__ __align__(16) u32 hp[2][512];     // h (bf16 pairs)

    const int tid = threadIdx.x;
    const int w = tid>>6, l = tid&63;
    const int bid = blockIdx.x;

    {   // pack x -> hp (bf16), zero SS
        const float2* xs = (const float2*)(x + (size_t)bid*2*1024);
        for (int k = tid; k < 1024; k += 512){
            float2 f = xs[k];
            ((u32*)hp)[k] = pk2(f.x, f.y);
        }
        for (int k = tid; k < 2048; k += 512) ((float*)SS)[k] = 0.f;
    }
    __syncthreads();

    run_layer<128, 8,64,16,0>(Wb0, X, SS, hp, out, bid, w, l, tid);
    run_layer< 64,16,32,32,0>(Wb1, X, SS, hp, out, bid, w, l, tid);
    run_layer< 32,32,10,64,1>(Wb2, X, SS, hp, out, bid, w, l, tid);
}

// ---------------- fallback (round-2 kernel, known-pass) ----------------
template<int I, int Di, int O, int Do, bool FINAL>
__device__ __forceinline__ void fb_layer(const float* __restrict__ W, float* __restrict__ hl,
                                         float* __restrict__ out, int e, int l) {
    constexpr int LPO = Do / 16;
    constexpr int ACT = O * LPO;
    const int o  = l / LPO;
    const int d0 = (l % LPO) * 16;
    const bool act = (l < ACT);
    float vs[16];
    #pragma unroll
    for (int j = 0; j < 16; ++j) vs[j] = 0.f;
    for (int r = 0; r < 3; ++r) {
        float sacc[16];
        #pragma unroll
        for (int j = 0; j < 16; ++j) sacc[j] = 0.f;
        for (int i = 0; i < I; ++i) {
            if ((i & 15) == 0) __syncthreads();
            float xh[16];
            #pragma unroll
            for (int j = 0; j < 16; ++j) xh[j] = 0.f;
            if (act) {
                const float* wb = W + ((size_t)(o * I + i) * Do + d0) * Di;
                #pragma unroll
                for (int j = 0; j < 16; ++j) {
                    const float4* wr = (const float4*)(wb + j * Di);
                    float acc = 0.f;
                    #pragma unroll
                    for (int c4 = 0; c4 < Di / 4; ++c4) {
                        float4 wv = wr[c4];
                        float4 hv = *(const float4*)(hl + i * Di + c4 * 4);
                        acc += wv.x*hv.x + wv.y*hv.y + wv.z*hv.z + wv.w*hv.w;
                    }
                    xh[j] = acc;
                }
            }
            float cc;
            if (r == 0) cc = 1.0f;
            else {
                float lp = 0.f;
                #pragma unroll
                for (int j = 0; j < 16; ++j) lp += vs[j] * xh[j];
                if constexpr (LPO >= 2) lp += __shfl_xor(lp, 1, 64);
                if constexpr (LPO >= 4) lp += __shfl_xor(lp, 2, 64);
                float ev = act ? __expf(lp) : 0.f;
                float tot = ev;
                tot += __shfl_xor(tot,1,64); tot += __shfl_xor(tot,2,64);
                tot += __shfl_xor(tot,4,64); tot += __shfl_xor(tot,8,64);
                tot += __shfl_xor(tot,16,64); tot += __shfl_xor(tot,32,64);
                cc = ev * (float)LPO / tot;
            }
            #pragma unroll
            for (int j = 0; j < 16; ++j) sacc[j] += cc * xh[j];
        }
        if (r == 0) {
            #pragma unroll
            for (int j = 0; j < 16; ++j) sacc[j] *= (1.0f / O);
        }
        float n2 = 0.f;
        #pragma unroll
        for (int j = 0; j < 16; ++j) n2 += sacc[j] * sacc[j];
        if constexpr (LPO >= 2) n2 += __shfl_xor(n2, 1, 64);
        if constexpr (LPO >= 4) n2 += __shfl_xor(n2, 2, 64);
        float nrm = sqrtf(n2);
        float scale = n2 / ((1.f + n2) * (nrm + 1e-8f));
        if (r < 2) {
            #pragma unroll
            for (int j = 0; j < 16; ++j) vs[j] += scale * sacc[j];
        } else {
            if constexpr (FINAL) {
                float q = 0.f;
                #pragma unroll
                for (int j = 0; j < 16; ++j) { float vj = scale*sacc[j]; q += vj*vj; }
                if constexpr (LPO >= 2) q += __shfl_xor(q, 1, 64);
                if constexpr (LPO >= 4) q += __shfl_xor(q, 2, 64);
                if (act && (l % LPO) == 0) out[(size_t)e * O + o] = sqrtf(q);
            } else {
                __syncthreads();
                if (act) {
                    #pragma unroll
                    for (int j = 0; j < 16; ++j) hl[o * Do + d0 + j] = scale * sacc[j];
                }
                __syncthreads();
            }
        }
    }
}

__global__ __launch_bounds__(256) void fb_caps(const float* __restrict__ x,
                                               const float* __restrict__ W0,
                                               const float* __restrict__ W1,
                                               const float* __restrict__ W2,
                                               float* __restrict__ out) {
    __shared__ float hsh[4][1024];
    const int w = threadIdx.x >> 6;
    const int l = threadIdx.x & 63;
    const int e = blockIdx.x * 4 + w;
    float* hl = hsh[w];
    const float4* xr = (const float4*)(x + (size_t)e * 1024);
    float4* h4 = (float4*)hl;
    #pragma unroll
    for (int k = 0; k < 4; ++k) h4[l + 64 * k] = xr[l + 64 * k];
    __syncthreads();
    fb_layer<128, 8, 64, 16, false>(W0, hl, out, e, l);
    fb_layer<64, 16, 32, 32, false>(W1, hl, out, e, l);
    fb_layer<32, 32, 10, 64, true >(W2, hl, out, e, l);
}

extern "C" void kernel_launch(void* const* d_in, const int* in_sizes, int n_in,
                              void* d_out, int out_size, void* d_ws, size_t ws_size,
                              hipStream_t stream) {
    const float* x  = (const float*)d_in[0];   // [1024,1024]
    const float* W0 = (const float*)d_in[1];   // [64,128,16,8]
    const float* W1 = (const float*)d_in[2];   // [32,64,32,16]
    const float* W2 = (const float*)d_in[3];   // [10,32,64,32]
    float* out = (float*)d_out;                // [1024,10]

    const size_t DW0 = (size_t)64*128*16*8/2;   // u32 counts
    const size_t DW1 = (size_t)32*64*32*16/2;
    const size_t DW2 = (size_t)10*32*64*32/2;
    const size_t need = (DW0+DW1+DW2)*4;        // ~5.5 MB

    if (ws_size < need) {                       // safety net: proven slow path
        fb_caps<<<256, 256, 0, stream>>>(x, W0, W1, W2, out);
        return;
    }

    u32* Wb0 = (u32*)d_ws;
    u32* Wb1 = Wb0 + DW0;
    u32* Wb2 = Wb1 + DW1;

    k_conv<128, 8,64,16><<<512,256,0,stream>>>(W0, Wb0);
    k_conv< 64,16,32,32><<<512,256,0,stream>>>(W1, Wb1);
    k_conv< 32,32,10,64><<<512,256,0,stream>>>(W2, Wb2);

    caps_main<<<512, 512, 0, stream>>>(x, Wb0, Wb1, Wb2, out);
}

// Round 10
// 725.709 us; speedup vs baseline: 2.5910x; 1.0297x over previous
//
#include <hip/hip_runtime.h>
#include <math.h>

typedef unsigned int u32;

// ---------- bf16 helpers ----------
__device__ __forceinline__ u32 pk2(float a, float b){
    u32 ua=__float_as_uint(a), ub=__float_as_uint(b);
    u32 ra=(ua + 0x7fffu + ((ua>>16)&1u))>>16;
    u32 rb=(ub + 0x7fffu + ((ub>>16)&1u))>>16;
    return ra | (rb<<16);
}
__device__ __forceinline__ float lo16(u32 p){ return __uint_as_float(p<<16); }
__device__ __forceinline__ float hi16(u32 p){ return __uint_as_float(p & 0xffff0000u); }

// packed bf16x2 dot-accumulate: c += a.x*b.x + a.y*b.y
#if __has_builtin(__builtin_amdgcn_fdot2_f32_bf16)
__device__ __forceinline__ float dot2bf(u32 a, u32 b, float c){
    float d;
    asm("v_dot2_f32_bf16 %0, %1, %2, %3" : "=v"(d) : "v"(a), "v"(b), "v"(c));
    return d;
}
#else
__device__ __forceinline__ float dot2bf(u32 a, u32 b, float c){
    return fmaf(hi16(a), hi16(b), fmaf(lo16(a), lo16(b), c));
}
#endif

// async global->LDS, 16B/lane; LDS dest = wave-uniform base + lane*16
__device__ __forceinline__ void gll16(const u32* gp, u32* lp){
    __builtin_amdgcn_global_load_lds((const __attribute__((address_space(1))) void*)gp,
                                     (__attribute__((address_space(3))) void*)lp,
                                     16, 0, 0);
}

// ---------- W convert ----------
// Staging-linear layout, uint4 granularity:
//   idx4 = ((((oct*SGRPS + sg)*WI + i_loc)*SP + s)*GR + g)
// with i = oct*WI + i_loc, slot = sg*SP+s = j*CB+cb, g = q*O+o,
// source element jg = q*16+j, c = cb*8 + cw*2  (pairs packed per u32).
template<int I,int Di,int O,int Do,int WI,int SP>
__global__ void k_conv(const float* __restrict__ W, u32* __restrict__ Wb){
    constexpr int CB=Di/8, LPO=Do/16, GR=LPO*O, NSL=16*CB, SGRPS=NSL/SP;
    const int n = O*I*Do*Di/2;
    for (int t = blockIdx.x*blockDim.x+threadIdx.x; t < n; t += gridDim.x*blockDim.x){
        int cw = t & 3;
        int u4 = t >> 2;
        int g  = u4 % GR;    int r1  = u4 / GR;
        int s  = r1 % SP;    int r2  = r1 / SP;
        int il = r2 % WI;    int r3  = r2 / WI;
        int sg = r3 % SGRPS; int oct = r3 / SGRPS;
        int i    = oct*WI + il;
        int slot = sg*SP + s;
        int j  = slot / CB, cb = slot % CB;
        int o  = g % O,     q  = g / O;
        int jg = q*16 + j;
        int c  = cb*8 + cw*2;
        const float* src = W + ((size_t)(o*I + i)*Do + jg)*Di + c;
        Wb[t] = pk2(src[0], src[1]);
    }
}

// ---------- fused layer: DMA-staged W, multiplicity-1, dot2 ----------
// 8 waves, each owns i = oct*8 + w for ALL 4 elements. Chunk = 8 i's x SP=8
// slots, double-buffered 64KB slabs via global_load_lds (zero VGPR staging).
// xh[4][16] accumulates across an i's SGRPS chunks; softmax + sacc at i-end.
// Pass-end: per-wave sacc -> dead slab (lane-major), tree-reduce, squash.
template<int I,int Di,int O,int Do,int FIN>
__device__ __forceinline__ void run_layer(const u32* __restrict__ Wb,
    u32* slab, float (*X)[1024], u32 (*hp)[512], float* __restrict__ out,
    int bid, int w, int l, int tid)
{
    constexpr int CB=Di/8, LPO=Do/16, ACT=O*LPO, GR=LPO*O;
    constexpr int NSL=16*CB, SP=8, SGRPS=NSL/SP, WI=8;
    constexpr int NOCT=I/WI;
    constexpr int CHU4=WI*SP*GR;     // uint4 per chunk
    constexpr int CHDW=CHU4*4;       // u32 per chunk
    constexpr int ROUNDS=CHDW/2048;  // 512 thr x 16B per round
    constexpr int NCH=NOCT*SGRPS;
    static_assert(SGRPS>=1 && (SGRPS&1)==0, "even chunks per i");
    static_assert(CHDW<=16384, "chunk fits 64KB buffer");

    const bool act = l < ACT;
    const int qL = act ? (l%LPO) : 0;
    const int oL = act ? (l/LPO) : 0;
    const int lnoff = qL*O + oL;     // per-lane uint4 offset within a slot
    float* red = (float*)slab;       // aliases slab between passes

    for (int r=0; r<3; ++r){
        u32 vp[4][8];
        if (r>0){
            #pragma unroll
            for (int eu=0; eu<4; ++eu)
                #pragma unroll
                for (int jj=0; jj<8; ++jj)
                    vp[eu][jj] = pk2(X[eu][(2*jj)*64+l], X[eu][(2*jj+1)*64+l]);
        }
        float sacc[4][16], xh[4][16];
        #pragma unroll
        for (int eu=0; eu<4; ++eu)
            #pragma unroll
            for (int j=0; j<16; ++j){ sacc[eu][j]=0.f; xh[eu][j]=0.f; }

        auto stage = [&](int c, int buf){
            const u32* g = Wb + (size_t)c*CHDW + tid*4;
            u32* ld = slab + buf*16384 + w*256;
            #pragma unroll
            for (int rd=0; rd<ROUNDS; ++rd)
                gll16(g + rd*2048, ld + rd*2048);
        };

        stage(0, 0);
        __syncthreads();                    // drain chunk 0

        for (int oct=0; oct<NOCT; ++oct){
            const int i = oct*WI + w;
            #pragma unroll
            for (int sg=0; sg<SGRPS; ++sg){
                const int c = oct*SGRPS + sg;
                if (c+1 < NCH) stage(c+1, (sg+1)&1);   // issue next-chunk DMA

                const uint4* wb4 = (const uint4*)(slab + (sg&1)*16384)
                                 + w*(SP*GR) + lnoff;
                u32 hk[4][(CB<=2 ? CB : 1)*4];
                if constexpr (CB<=2){
                    #pragma unroll
                    for (int eu=0; eu<4; ++eu)
                        #pragma unroll
                        for (int cb2=0; cb2<CB; ++cb2){
                            uint4 hv = *(const uint4*)&hp[eu][i*(Di/2)+cb2*4];
                            hk[eu][cb2*4+0]=hv.x; hk[eu][cb2*4+1]=hv.y;
                            hk[eu][cb2*4+2]=hv.z; hk[eu][cb2*4+3]=hv.w;
                        }
                }
                #pragma unroll
                for (int s=0; s<SP; ++s){
                    const int slot = sg*SP + s;        // compile-time (sg,s unrolled)
                    const int j = slot/CB, cb = slot%CB;
                    uint4 wv = wb4[s*GR];
                    u32 ha[4][4];
                    if constexpr (CB==4){
                        #pragma unroll
                        for (int eu=0; eu<4; ++eu){
                            uint4 hv = *(const uint4*)&hp[eu][i*(Di/2)+cb*4];
                            ha[eu][0]=hv.x; ha[eu][1]=hv.y; ha[eu][2]=hv.z; ha[eu][3]=hv.w;
                        }
                    } else {
                        #pragma unroll
                        for (int eu=0; eu<4; ++eu)
                            #pragma unroll
                            for (int k2=0; k2<4; ++k2) ha[eu][k2] = hk[eu][cb*4+k2];
                    }
                    #pragma unroll
                    for (int eu=0; eu<4; ++eu){
                        float t2 = xh[eu][j];
                        t2 = dot2bf(wv.x, ha[eu][0], t2);
                        t2 = dot2bf(wv.y, ha[eu][1], t2);
                        t2 = dot2bf(wv.z, ha[eu][2], t2);
                        t2 = dot2bf(wv.w, ha[eu][3], t2);
                        xh[eu][j] = t2;
                    }
                }
                if (sg == SGRPS-1){                    // i complete: fold into sacc
                    float cc[4];
                    if (r==0){
                        #pragma unroll
                        for (int eu=0; eu<4; ++eu) cc[eu] = 1.f;  // 1/O at squash
                    } else {
                        #pragma unroll
                        for (int eu=0; eu<4; ++eu){
                            float lp = 0.f;
                            #pragma unroll
                            for (int jj=0; jj<8; ++jj)
                                lp += lo16(vp[eu][jj])*xh[eu][2*jj]
                                    + hi16(vp[eu][jj])*xh[eu][2*jj+1];
                            if constexpr (LPO>=2) lp += __shfl_xor(lp,1,64);
                            if constexpr (LPO>=4) lp += __shfl_xor(lp,2,64);
                            float ev = act ? __expf(lp) : 0.f;
                            float tot = ev;            // each o counted LPO times
                            tot+=__shfl_xor(tot,1,64);  tot+=__shfl_xor(tot,2,64);
                            tot+=__shfl_xor(tot,4,64);  tot+=__shfl_xor(tot,8,64);
                            tot+=__shfl_xor(tot,16,64); tot+=__shfl_xor(tot,32,64);
                            cc[eu] = ev*(float)LPO/tot;
                        }
                    }
                    #pragma unroll
                    for (int eu=0; eu<4; ++eu)
                        #pragma unroll
                        for (int j=0; j<16; ++j){
                            sacc[eu][j] += cc[eu]*xh[eu][j];
                            xh[eu][j] = 0.f;
                        }
                }
                __syncthreads();    // drains DMA; guards buffer swap
            }
        }

        // per-wave partials -> dead slab (lane-major, conflict-free)
        if (act){
            #pragma unroll
            for (int eu=0; eu<4; ++eu)
                #pragma unroll
                for (int j=0; j<16; ++j)
                    red[(w*4+eu)*1024 + j*64 + l] = sacc[eu][j];
        }
        __syncthreads();
        // 512-thread tree reduce over 8 wave-partials (into p=0 slots)
        for (int t2=tid; t2<4096; t2+=512){
            int e = t2>>10, k = t2&1023;
            float s2 = 0.f;
            #pragma unroll
            for (int p=0; p<8; ++p) s2 += red[(p*4+e)*1024 + k];
            red[e*1024 + k] = s2;
        }
        __syncthreads();

        // squash: wave e handles element e
        if (w < 4){
            const int e = w;
            float s[16];
            #pragma unroll
            for (int j=0; j<16; ++j){
                float t2 = red[e*1024 + j*64 + l];
                if (r==0) t2 *= (1.0f/(float)O);
                s[j] = t2;
            }
            float n2 = 0.f;
            #pragma unroll
            for (int j=0; j<16; ++j) n2 += s[j]*s[j];
            if constexpr (LPO>=2) n2 += __shfl_xor(n2,1,64);
            if constexpr (LPO>=4) n2 += __shfl_xor(n2,2,64);
            float nrm   = sqrtf(n2);
            float scale = n2/((1.f+n2)*(nrm+1e-8f));

            if (r < 2){
                if (act){
                    #pragma unroll
                    for (int j=0; j<16; ++j){
                        float old = (r==0) ? 0.f : X[e][j*64+l];
                        X[e][j*64+l] = old + scale*s[j];    // vs += v (affine carry)
                    }
                }
            } else if constexpr (FIN==0){
                if (act){
                    #pragma unroll
                    for (int kk=0; kk<8; ++kk)
                        hp[e][oL*(Do/2) + qL*8 + kk] = pk2(scale*s[2*kk], scale*s[2*kk+1]);
                }
            } else {
                float q = 0.f;
                #pragma unroll
                for (int j=0; j<16; ++j){ float vj = scale*s[j]; q += vj*vj; }
                if constexpr (LPO>=2) q += __shfl_xor(q,1,64);
                if constexpr (LPO>=4) q += __shfl_xor(q,2,64);
                if (act && (l%LPO)==0)
                    out[(size_t)(bid*4 + e)*O + oL] = sqrtf(q);
            }
        }
        __syncthreads();   // closes pass: X/hp visible; red free for next stage
    }
}

__global__ __launch_bounds__(512,1) void caps_main(
    const float* __restrict__ x, const u32* __restrict__ Wb0,
    const u32* __restrict__ Wb1, const u32* __restrict__ Wb2,
    float* __restrict__ out)
{
    __shared__ __align__(16) u32 slab[32768];   // 2 x 64KB W chunks (red aliases)
    __shared__ __align__(16) float X[4][1024];  // vs state (lane-major), 16KB
    __shared__ __align__(16) u32 hp[4][512];    // h (bf16 pairs), 8KB

    const int tid = threadIdx.x;
    const int w = tid>>6, l = tid&63;
    const int bid = blockIdx.x;

    {   // pack x -> hp (bf16)
        const float2* xs = (const float2*)(x + (size_t)bid*4*1024);
        for (int k = tid; k < 2048; k += 512){
            float2 f = xs[k];
            ((u32*)hp)[k] = pk2(f.x, f.y);
        }
    }
    __syncthreads();

    run_layer<128, 8,64,16,0>(Wb0, slab, X, hp, out, bid, w, l, tid);
    run_layer< 64,16,32,32,0>(Wb1, slab, X, hp, out, bid, w, l, tid);
    run_layer< 32,32,10,64,1>(Wb2, slab, X, hp, out, bid, w, l, tid);
}

// ---------------- fallback (round-2 kernel, known-pass) ----------------
template<int I, int Di, int O, int Do, bool FINAL>
__device__ __forceinline__ void fb_layer(const float* __restrict__ W, float* __restrict__ hl,
                                         float* __restrict__ out, int e, int l) {
    constexpr int LPO = Do / 16;
    constexpr int ACT = O * LPO;
    const int o  = l / LPO;
    const int d0 = (l % LPO) * 16;
    const bool act = (l < ACT);
    float vs[16];
    #pragma unroll
    for (int j = 0; j < 16; ++j) vs[j] = 0.f;
    for (int r = 0; r < 3; ++r) {
        float sacc[16];
        #pragma unroll
        for (int j = 0; j < 16; ++j) sacc[j] = 0.f;
        for (int i = 0; i < I; ++i) {
            if ((i & 15) == 0) __syncthreads();
            float xh[16];
            #pragma unroll
            for (int j = 0; j < 16; ++j) xh[j] = 0.f;
            if (act) {
                const float* wb = W + ((size_t)(o * I + i) * Do + d0) * Di;
                #pragma unroll
                for (int j = 0; j < 16; ++j) {
                    const float4* wr = (const float4*)(wb + j * Di);
                    float acc = 0.f;
                    #pragma unroll
                    for (int c4 = 0; c4 < Di / 4; ++c4) {
                        float4 wv = wr[c4];
                        float4 hv = *(const float4*)(hl + i * Di + c4 * 4);
                        acc += wv.x*hv.x + wv.y*hv.y + wv.z*hv.z + wv.w*hv.w;
                    }
                    xh[j] = acc;
                }
            }
            float cc;
            if (r == 0) cc = 1.0f;
            else {
                float lp = 0.f;
                #pragma unroll
                for (int j = 0; j < 16; ++j) lp += vs[j] * xh[j];
                if constexpr (LPO >= 2) lp += __shfl_xor(lp, 1, 64);
                if constexpr (LPO >= 4) lp += __shfl_xor(lp, 2, 64);
                float ev = act ? __expf(lp) : 0.f;
                float tot = ev;
                tot += __shfl_xor(tot,1,64); tot += __shfl_xor(tot,2,64);
                tot += __shfl_xor(tot,4,64); tot += __shfl_xor(tot,8,64);
                tot += __shfl_xor(tot,16,64); tot += __shfl_xor(tot,32,64);
                cc = ev * (float)LPO / tot;
            }
            #pragma unroll
            for (int j = 0; j < 16; ++j) sacc[j] += cc * xh[j];
        }
        if (r == 0) {
            #pragma unroll
            for (int j = 0; j < 16; ++j) sacc[j] *= (1.0f / O);
        }
        float n2 = 0.f;
        #pragma unroll
        for (int j = 0; j < 16; ++j) n2 += sacc[j] * sacc[j];
        if constexpr (LPO >= 2) n2 += __shfl_xor(n2, 1, 64);
        if constexpr (LPO >= 4) n2 += __shfl_xor(n2, 2, 64);
        float nrm = sqrtf(n2);
        float scale = n2 / ((1.f + n2) * (nrm + 1e-8f));
        if (r < 2) {
            #pragma unroll
            for (int j = 0; j < 16; ++j) vs[j] += scale * sacc[j];
        } else {
            if constexpr (FINAL) {
                float q = 0.f;
                #pragma unroll
                for (int j = 0; j < 16; ++j) { float vj = scale*sacc[j]; q += vj*vj; }
                if constexpr (LPO >= 2) q += __shfl_xor(q, 1, 64);
                if constexpr (LPO >= 4) q += __shfl_xor(q, 2, 64);
                if (act && (l % LPO) == 0) out[(size_t)e * O + o] = sqrtf(q);
            } else {
                __syncthreads();
                if (act) {
                    #pragma unroll
                    for (int j = 0; j < 16; ++j) hl[o * Do + d0 + j] = scale * sacc[j];
                }
                __syncthreads();
            }
        }
    }
}

__global__ __launch_bounds__(256) void fb_caps(const float* __restrict__ x,
                                               const float* __restrict__ W0,
                                               const float* __restrict__ W1,
                                               const float* __restrict__ W2,
                                               float* __restrict__ out) {
    __shared__ float hsh[4][1024];
    const int w = threadIdx.x >> 6;
    const int l = threadIdx.x & 63;
    const int e = blockIdx.x * 4 + w;
    float* hl = hsh[w];
    const float4* xr = (const float4*)(x + (size_t)e * 1024);
    float4* h4 = (float4*)hl;
    #pragma unroll
    for (int k = 0; k < 4; ++k) h4[l + 64 * k] = xr[l + 64 * k];
    __syncthreads();
    fb_layer<128, 8, 64, 16, false>(W0, hl, out, e, l);
    fb_layer<64, 16, 32, 32, false>(W1, hl, out, e, l);
    fb_layer<32, 32, 10, 64, true >(W2, hl, out, e, l);
}

extern "C" void kernel_launch(void* const* d_in, const int* in_sizes, int n_in,
                              void* d_out, int out_size, void* d_ws, size_t ws_size,
                              hipStream_t stream) {
    const float* x  = (const float*)d_in[0];   // [1024,1024]
    const float* W0 = (const float*)d_in[1];   // [64,128,16,8]
    const float* W1 = (const float*)d_in[2];   // [32,64,32,16]
    const float* W2 = (const float*)d_in[3];   // [10,32,64,32]
    float* out = (float*)d_out;                // [1024,10]

    const size_t DW0 = (size_t)64*128*16*8/2;   // u32 counts
    const size_t DW1 = (size_t)32*64*32*16/2;
    const size_t DW2 = (size_t)10*32*64*32/2;
    const size_t need = (DW0+DW1+DW2)*4;        // ~5.5 MB

    if (ws_size < need) {                       // safety net: proven slow path
        fb_caps<<<256, 256, 0, stream>>>(x, W0, W1, W2, out);
        return;
    }

    u32* Wb0 = (u32*)d_ws;
    u32* Wb1 = Wb0 + DW0;
    u32* Wb2 = Wb1 + DW1;

    k_conv<128, 8,64,16,8,8><<<512,256,0,stream>>>(W0, Wb0);
    k_conv< 64,16,32,32,8,8><<<512,256,0,stream>>>(W1, Wb1);
    k_conv< 32,32,10,64,8,8><<<512,256,0,stream>>>(W2, Wb2);

    caps_main<<<256, 512, 0, stream>>>(x, Wb0, Wb1, Wb2, out);
}

// Round 11
// 477.633 us; speedup vs baseline: 3.9367x; 1.5194x over previous
//
#include <hip/hip_runtime.h>
#include <math.h>

typedef unsigned int u32;

// ---------- bf16 helpers ----------
__device__ __forceinline__ u32 pk2(float a, float b){
    u32 ua=__float_as_uint(a), ub=__float_as_uint(b);
    u32 ra=(ua + 0x7fffu + ((ua>>16)&1u))>>16;
    u32 rb=(ub + 0x7fffu + ((ub>>16)&1u))>>16;
    return ra | (rb<<16);
}
__device__ __forceinline__ float lo16(u32 p){ return __uint_as_float(p<<16); }
__device__ __forceinline__ float hi16(u32 p){ return __uint_as_float(p & 0xffff0000u); }

#if __has_builtin(__builtin_amdgcn_fdot2_f32_bf16)
__device__ __forceinline__ float dot2bf(u32 a, u32 b, float c){
    float d;
    asm("v_dot2_f32_bf16 %0, %1, %2, %3" : "=v"(d) : "v"(a), "v"(b), "v"(c));
    return d;
}
#else
__device__ __forceinline__ float dot2bf(u32 a, u32 b, float c){
    return fmaf(hi16(a), hi16(b), fmaf(lo16(a), lo16(b), c));
}
#endif

// async global->LDS, 16B/lane
__device__ __forceinline__ void gll16(const u32* gp, u32* lp){
    __builtin_amdgcn_global_load_lds((const __attribute__((address_space(1))) void*)gp,
                                     (__attribute__((address_space(3))) void*)lp,
                                     16, 0, 0);
}

// ---------- W convert: fp32 [o][i][jg][c] -> bf16 pairs, layout [si][il][slot][g][cw]
// slot=j*CB+cb (j 0..15), g=q*O+o, jg=q*16+j, c=cb*8+cw*2
template<int I,int Di,int O,int Do,int IR>
__global__ void k_conv(const float* __restrict__ W, u32* __restrict__ Wb){
    constexpr int CB=Di/8, LPO=Do/16, GR=LPO*O, NSL=16*CB;
    const int n = O*I*Do*Di/2;
    for (int t = blockIdx.x*blockDim.x+threadIdx.x; t < n; t += gridDim.x*blockDim.x){
        int cw = t & 3;
        int u4 = t >> 2;
        int g    = u4 % GR;  int r1 = u4 / GR;
        int slot = r1 % NSL; int r2 = r1 / NSL;
        int il   = r2 % IR;  int si = r2 / IR;
        int i  = si*IR + il;
        int j  = slot / CB, cb = slot % CB;
        int o  = g % O,     q  = g / O;
        int jg = q*16 + j;
        int c  = cb*8 + cw*2;
        const float* src = W + ((size_t)(o*I + i)*Do + jg)*Di + c;
        Wb[t] = pk2(src[0], src[1]);
    }
}

// ---------- contract: one i-slice (si) x one element-group (eg) ----------
// W-slice staged in LDS ONCE; 8 waves each own 8 elements independently
// (NO barriers after staging, NO cross-wave reduction). Lane l: o=l/LPO,
// d-block q=l%LPO. Partial s written bf16 to ps[si][e][od-pairs].
template<int I,int Di,int O,int Do,int IR,int ES,bool LOGIT,bool XS>
__global__ __launch_bounds__(512,1) void k_contract(
    const u32* __restrict__ Wb, const void* __restrict__ hsrc,
    const u32* __restrict__ vsb, u32* __restrict__ ps)
{
    constexpr int CB=Di/8, LPO=Do/16, ACT=O*LPO, GR=LPO*O, NSL=16*CB;
    constexpr int SLICE  = IR*NSL*GR*4;     // u32 per slice
    constexpr int ROUNDS = SLICE/2048;      // 512 thr x 16B rounds
    __shared__ __align__(16) u32 slab[SLICE];

    const int tid = threadIdx.x;
    const int w = tid>>6, l = tid&63;
    const int eg = blockIdx.x, si = blockIdx.y;

    {   // stage W-slice once
        const u32* g = Wb + (size_t)si*SLICE + tid*4;
        u32* ld = slab + w*256;
        #pragma unroll
        for (int rd=0; rd<ROUNDS; ++rd) gll16(g + rd*2048, ld + rd*2048);
    }
    __syncthreads();   // drains DMA; only barrier in the kernel

    const bool act = l < ACT;
    const int qL = act ? (l%LPO) : 0;
    const int oL = act ? (l/LPO) : 0;
    const int lnoff = qL*O + oL;
    const uint4* W4 = (const uint4*)slab;

    for (int ee=0; ee<8/ES; ++ee){
        const int e0 = eg*64 + w*8 + ee*ES;

        u32 vp[ES][8];
        if constexpr (LOGIT){
            #pragma unroll
            for (int k=0;k<ES;++k){
                uint4 a = *(const uint4*)(vsb + (size_t)(e0+k)*512 + l*8);
                uint4 b = *(const uint4*)(vsb + (size_t)(e0+k)*512 + l*8 + 4);
                vp[k][0]=a.x; vp[k][1]=a.y; vp[k][2]=a.z; vp[k][3]=a.w;
                vp[k][4]=b.x; vp[k][5]=b.y; vp[k][6]=b.z; vp[k][7]=b.w;
            }
        }

        float sacc[ES][16];
        #pragma unroll
        for (int k=0;k<ES;++k)
            #pragma unroll
            for (int j=0;j<16;++j) sacc[k][j]=0.f;

        for (int il=0; il<IR; ++il){
            // h fragment (bf16 pairs)
            u32 hk[ES][Di/2];
            if constexpr (XS){
                #pragma unroll
                for (int k=0;k<ES;++k){
                    const float* xp = (const float*)hsrc + (size_t)(e0+k)*1024 + (si*IR+il)*Di;
                    #pragma unroll
                    for (int f4=0; f4<Di/4; ++f4){
                        float4 f = *(const float4*)(xp + 4*f4);
                        hk[k][2*f4+0] = pk2(f.x, f.y);
                        hk[k][2*f4+1] = pk2(f.z, f.w);
                    }
                }
            } else {
                #pragma unroll
                for (int k=0;k<ES;++k){
                    const u32* hp = (const u32*)hsrc + (size_t)(e0+k)*512 + (si*IR+il)*(Di/2);
                    #pragma unroll
                    for (int t4=0; t4<Di/8; ++t4){
                        uint4 hv = *(const uint4*)(hp + 4*t4);
                        hk[k][4*t4+0]=hv.x; hk[k][4*t4+1]=hv.y;
                        hk[k][4*t4+2]=hv.z; hk[k][4*t4+3]=hv.w;
                    }
                }
            }

            float xh[ES][16];
            #pragma unroll
            for (int k=0;k<ES;++k)
                #pragma unroll
                for (int j=0;j<16;++j) xh[k][j]=0.f;

            #pragma unroll
            for (int j=0;j<16;++j)
                #pragma unroll
                for (int cb=0;cb<CB;++cb){
                    uint4 wv = W4[(il*NSL + j*CB + cb)*GR + lnoff];
                    #pragma unroll
                    for (int k=0;k<ES;++k){
                        float t = xh[k][j];
                        t = dot2bf(wv.x, hk[k][cb*4+0], t);
                        t = dot2bf(wv.y, hk[k][cb*4+1], t);
                        t = dot2bf(wv.z, hk[k][cb*4+2], t);
                        t = dot2bf(wv.w, hk[k][cb*4+3], t);
                        xh[k][j] = t;
                    }
                }

            float cc[ES];
            if constexpr (!LOGIT){
                #pragma unroll
                for (int k=0;k<ES;++k) cc[k]=1.f;       // 1/O folded at squash
            } else {
                #pragma unroll
                for (int k=0;k<ES;++k){
                    float lp=0.f;
                    #pragma unroll
                    for (int jj=0;jj<8;++jj)
                        lp += lo16(vp[k][jj])*xh[k][2*jj] + hi16(vp[k][jj])*xh[k][2*jj+1];
                    if constexpr (LPO>=2) lp += __shfl_xor(lp,1,64);
                    if constexpr (LPO>=4) lp += __shfl_xor(lp,2,64);
                    float ev = act ? __expf(lp) : 0.f;
                    float tot = ev;                     // each o counted LPO times
                    tot+=__shfl_xor(tot,1,64);  tot+=__shfl_xor(tot,2,64);
                    tot+=__shfl_xor(tot,4,64);  tot+=__shfl_xor(tot,8,64);
                    tot+=__shfl_xor(tot,16,64); tot+=__shfl_xor(tot,32,64);
                    cc[k] = ev*(float)LPO/tot;
                }
            }
            #pragma unroll
            for (int k=0;k<ES;++k)
                #pragma unroll
                for (int j=0;j<16;++j) sacc[k][j] += cc[k]*xh[k][j];
        }

        if (act){
            #pragma unroll
            for (int k=0;k<ES;++k){
                u32* pp = ps + ((size_t)(si*1024 + e0 + k))*512 + l*8;
                uint4 o0, o1;
                o0.x=pk2(sacc[k][0],sacc[k][1]);   o0.y=pk2(sacc[k][2],sacc[k][3]);
                o0.z=pk2(sacc[k][4],sacc[k][5]);   o0.w=pk2(sacc[k][6],sacc[k][7]);
                o1.x=pk2(sacc[k][8],sacc[k][9]);   o1.y=pk2(sacc[k][10],sacc[k][11]);
                o1.z=pk2(sacc[k][12],sacc[k][13]); o1.w=pk2(sacc[k][14],sacc[k][15]);
                *(uint4*)pp = o0;
                *(uint4*)(pp+4) = o1;
            }
        }
    }
}

// ---------- squash: reduce 16 slice-partials, squash, update state ----------
// MODE 0: vs = v (and fold 1/O). 1: vs += v. 2: hnext = v. 3: out = ||v||.
template<int O,int Do,int MODE>
__global__ __launch_bounds__(256) void k_squash(
    const u32* __restrict__ ps, u32* __restrict__ vsb, void* __restrict__ dst)
{
    constexpr int LPO=Do/16, ACT=O*LPO;
    const int tid=threadIdx.x, w=tid>>6, l=tid&63;
    const int e = blockIdx.x*4 + w;
    const bool act = l < ACT;
    const int oL = act ? (l/LPO) : 0;

    float s[16];
    #pragma unroll
    for (int j=0;j<16;++j) s[j]=0.f;
    #pragma unroll
    for (int si=0; si<16; ++si){
        const u32* pp = ps + ((size_t)(si*1024 + e))*512 + l*8;
        uint4 a = *(const uint4*)pp;
        uint4 b = *(const uint4*)(pp+4);
        u32 q[8] = {a.x,a.y,a.z,a.w,b.x,b.y,b.z,b.w};
        #pragma unroll
        for (int k=0;k<8;++k){ s[2*k] += lo16(q[k]); s[2*k+1] += hi16(q[k]); }
    }
    if constexpr (MODE==0){
        #pragma unroll
        for (int j=0;j<16;++j) s[j] *= (1.0f/(float)O);
    }
    float n2=0.f;
    #pragma unroll
    for (int j=0;j<16;++j) n2 += s[j]*s[j];
    if constexpr (LPO>=2) n2 += __shfl_xor(n2,1,64);
    if constexpr (LPO>=4) n2 += __shfl_xor(n2,2,64);
    float nrm   = sqrtf(n2);
    float scale = n2/((1.f+n2)*(nrm+1e-8f));

    if constexpr (MODE==0){
        if (act){
            u32* vp = vsb + (size_t)e*512 + l*8;
            #pragma unroll
            for (int k=0;k<8;++k) vp[k] = pk2(scale*s[2*k], scale*s[2*k+1]);
        }
    } else if constexpr (MODE==1){
        if (act){
            u32* vp = vsb + (size_t)e*512 + l*8;
            #pragma unroll
            for (int k=0;k<8;++k){
                u32 old = vp[k];
                vp[k] = pk2(lo16(old)+scale*s[2*k], hi16(old)+scale*s[2*k+1]);
            }
        }
    } else if constexpr (MODE==2){
        if (act){
            u32* hp = (u32*)dst + (size_t)e*512 + l*8;
            #pragma unroll
            for (int k=0;k<8;++k) hp[k] = pk2(scale*s[2*k], scale*s[2*k+1]);
        }
    } else {
        float q=0.f;
        #pragma unroll
        for (int j=0;j<16;++j){ float vj=scale*s[j]; q += vj*vj; }
        if constexpr (LPO>=2) q += __shfl_xor(q,1,64);
        if constexpr (LPO>=4) q += __shfl_xor(q,2,64);
        if (act && (l%LPO)==0)
            ((float*)dst)[(size_t)e*O + oL] = sqrtf(q);
    }
}

// ---------------- fallback (round-2 kernel, known-pass) ----------------
template<int I, int Di, int O, int Do, bool FINAL>
__device__ __forceinline__ void fb_layer(const float* __restrict__ W, float* __restrict__ hl,
                                         float* __restrict__ out, int e, int l) {
    constexpr int LPO = Do / 16;
    constexpr int ACT = O * LPO;
    const int o  = l / LPO;
    const int d0 = (l % LPO) * 16;
    const bool act = (l < ACT);
    float vs[16];
    #pragma unroll
    for (int j = 0; j < 16; ++j) vs[j] = 0.f;
    for (int r = 0; r < 3; ++r) {
        float sacc[16];
        #pragma unroll
        for (int j = 0; j < 16; ++j) sacc[j] = 0.f;
        for (int i = 0; i < I; ++i) {
            if ((i & 15) == 0) __syncthreads();
            float xh[16];
            #pragma unroll
            for (int j = 0; j < 16; ++j) xh[j] = 0.f;
            if (act) {
                const float* wb = W + ((size_t)(o * I + i) * Do + d0) * Di;
                #pragma unroll
                for (int j = 0; j < 16; ++j) {
                    const float4* wr = (const float4*)(wb + j * Di);
                    float acc = 0.f;
                    #pragma unroll
                    for (int c4 = 0; c4 < Di / 4; ++c4) {
                        float4 wv = wr[c4];
                        float4 hv = *(const float4*)(hl + i * Di + c4 * 4);
                        acc += wv.x*hv.x + wv.y*hv.y + wv.z*hv.z + wv.w*hv.w;
                    }
                    xh[j] = acc;
                }
            }
            float cc;
            if (r == 0) cc = 1.0f;
            else {
                float lp = 0.f;
                #pragma unroll
                for (int j = 0; j < 16; ++j) lp += vs[j] * xh[j];
                if constexpr (LPO >= 2) lp += __shfl_xor(lp, 1, 64);
                if constexpr (LPO >= 4) lp += __shfl_xor(lp, 2, 64);
                float ev = act ? __expf(lp) : 0.f;
                float tot = ev;
                tot += __shfl_xor(tot,1,64); tot += __shfl_xor(tot,2,64);
                tot += __shfl_xor(tot,4,64); tot += __shfl_xor(tot,8,64);
                tot += __shfl_xor(tot,16,64); tot += __shfl_xor(tot,32,64);
                cc = ev * (float)LPO / tot;
            }
            #pragma unroll
            for (int j = 0; j < 16; ++j) sacc[j] += cc * xh[j];
        }
        if (r == 0) {
            #pragma unroll
            for (int j = 0; j < 16; ++j) sacc[j] *= (1.0f / O);
        }
        float n2 = 0.f;
        #pragma unroll
        for (int j = 0; j < 16; ++j) n2 += sacc[j] * sacc[j];
        if constexpr (LPO >= 2) n2 += __shfl_xor(n2, 1, 64);
        if constexpr (LPO >= 4) n2 += __shfl_xor(n2, 2, 64);
        float nrm = sqrtf(n2);
        float scale = n2 / ((1.f + n2) * (nrm + 1e-8f));
        if (r < 2) {
            #pragma unroll
            for (int j = 0; j < 16; ++j) vs[j] += scale * sacc[j];
        } else {
            if constexpr (FINAL) {
                float q = 0.f;
                #pragma unroll
                for (int j = 0; j < 16; ++j) { float vj = scale*sacc[j]; q += vj*vj; }
                if constexpr (LPO >= 2) q += __shfl_xor(q, 1, 64);
                if constexpr (LPO >= 4) q += __shfl_xor(q, 2, 64);
                if (act && (l % LPO) == 0) out[(size_t)e * O + o] = sqrtf(q);
            } else {
                __syncthreads();
                if (act) {
                    #pragma unroll
                    for (int j = 0; j < 16; ++j) hl[o * Do + d0 + j] = scale * sacc[j];
                }
                __syncthreads();
            }
        }
    }
}

__global__ __launch_bounds__(256) void fb_caps(const float* __restrict__ x,
                                               const float* __restrict__ W0,
                                               const float* __restrict__ W1,
                                               const float* __restrict__ W2,
                                               float* __restrict__ out) {
    __shared__ float hsh[4][1024];
    const int w = threadIdx.x >> 6;
    const int l = threadIdx.x & 63;
    const int e = blockIdx.x * 4 + w;
    float* hl = hsh[w];
    const float4* xr = (const float4*)(x + (size_t)e * 1024);
    float4* h4 = (float4*)hl;
    #pragma unroll
    for (int k = 0; k < 4; ++k) h4[l + 64 * k] = xr[l + 64 * k];
    __syncthreads();
    fb_layer<128, 8, 64, 16, false>(W0, hl, out, e, l);
    fb_layer<64, 16, 32, 32, false>(W1, hl, out, e, l);
    fb_layer<32, 32, 10, 64, true >(W2, hl, out, e, l);
}

extern "C" void kernel_launch(void* const* d_in, const int* in_sizes, int n_in,
                              void* d_out, int out_size, void* d_ws, size_t ws_size,
                              hipStream_t stream) {
    const float* x  = (const float*)d_in[0];   // [1024,1024]
    const float* W0 = (const float*)d_in[1];   // [64,128,16,8]
    const float* W1 = (const float*)d_in[2];   // [32,64,32,16]
    const float* W2 = (const float*)d_in[3];   // [10,32,64,32]
    float* out = (float*)d_out;                // [1024,10]

    const size_t DW0 = 524288, DW1 = 524288, DW2 = 327680;   // u32
    const size_t DPS = (size_t)16*1024*512;                  // 8388608 u32
    const size_t DVS = (size_t)1024*512;                     // bf16-pair vs
    const size_t DH  = (size_t)1024*512;                     // h buffers
    const size_t need = (DW0+DW1+DW2+DPS+DVS+2*DH)*4;        // 45,350,912 B

    if (ws_size < need) {                       // safety net: proven slow path
        fb_caps<<<256, 256, 0, stream>>>(x, W0, W1, W2, out);
        return;
    }

    u32* Wb0 = (u32*)d_ws;
    u32* Wb1 = Wb0 + DW0;
    u32* Wb2 = Wb1 + DW1;
    u32* ps  = Wb2 + DW2;
    u32* vs  = ps  + DPS;
    u32* h1  = vs  + DVS;
    u32* h2  = h1  + DH;

    k_conv<128, 8,64,16,8><<<256,256,0,stream>>>(W0, Wb0);
    k_conv< 64,16,32,32,4><<<256,256,0,stream>>>(W1, Wb1);
    k_conv< 32,32,10,64,2><<<256,256,0,stream>>>(W2, Wb2);

    dim3 g(16,16);

    // layer 0: I=128 Di=8 O=64 Do=16, IR=8, ES=4, x fp32 source
    k_contract<128,8,64,16,8,4,false,true ><<<g,512,0,stream>>>(Wb0, x, vs, ps);
    k_squash<64,16,0><<<256,256,0,stream>>>(ps, vs, nullptr);
    k_contract<128,8,64,16,8,4,true ,true ><<<g,512,0,stream>>>(Wb0, x, vs, ps);
    k_squash<64,16,1><<<256,256,0,stream>>>(ps, vs, nullptr);
    k_contract<128,8,64,16,8,4,true ,true ><<<g,512,0,stream>>>(Wb0, x, vs, ps);
    k_squash<64,16,2><<<256,256,0,stream>>>(ps, vs, h1);

    // layer 1: I=64 Di=16 O=32 Do=32, IR=4, ES=4
    k_contract<64,16,32,32,4,4,false,false><<<g,512,0,stream>>>(Wb1, h1, vs, ps);
    k_squash<32,32,0><<<256,256,0,stream>>>(ps, vs, nullptr);
    k_contract<64,16,32,32,4,4,true ,false><<<g,512,0,stream>>>(Wb1, h1, vs, ps);
    k_squash<32,32,1><<<256,256,0,stream>>>(ps, vs, nullptr);
    k_contract<64,16,32,32,4,4,true ,false><<<g,512,0,stream>>>(Wb1, h1, vs, ps);
    k_squash<32,32,2><<<256,256,0,stream>>>(ps, vs, h2);

    // layer 2: I=32 Di=32 O=10 Do=64, IR=2, ES=2
    k_contract<32,32,10,64,2,2,false,false><<<g,512,0,stream>>>(Wb2, h2, vs, ps);
    k_squash<10,64,0><<<256,256,0,stream>>>(ps, vs, nullptr);
    k_contract<32,32,10,64,2,2,true ,false><<<g,512,0,stream>>>(Wb2, h2, vs, ps);
    k_squash<10,64,1><<<256,256,0,stream>>>(ps, vs, nullptr);
    k_contract<32,32,10,64,2,2,true ,false><<<g,512,0,stream>>>(Wb2, h2, vs, ps);
    k_squash<10,64,3><<<256,256,0,stream>>>(ps, vs, out);
}